// Round 10
// baseline (3178.259 us; speedup 1.0000x reference)
//
#include <hip/hip_runtime.h>
#include <hip/hip_bf16.h>
#include <math.h>

#define Bc 128
#define Tc 128
#define Hc 768
#define NHEAD 12
#define DKc 64
#define RHc 512
#define G4c 2048
#define NTc 10
#define LNEPS 1e-5f
#define NSLC 16   // blocks per LSTM group

typedef short bf16x8 __attribute__((ext_vector_type(8)));
typedef float f32x4 __attribute__((ext_vector_type(4)));

__device__ __forceinline__ float sigmoidf_(float x) { return 1.0f / (1.0f + __expf(-x)); }

__device__ __forceinline__ ushort f2bf(float f) {
  union { float f; uint u; } c; c.f = f;
  uint r = (c.u + 0x7FFFu + ((c.u >> 16) & 1u)) >> 16;
  return (ushort)r;
}
__device__ __forceinline__ float bf2f(ushort u) {
  union { uint u; float f; } c; c.u = ((uint)u) << 16;
  return c.f;
}
__device__ __forceinline__ uint pack2(float a, float b) {
  return (uint)f2bf(a) | ((uint)f2bf(b) << 16);
}

// bsum permuted to gate-interleaved order: out[u*4+g] = b_ih[g*512+u] + b_hh[g*512+u]
__global__ void bias_sum_perm_k(const float* __restrict__ a, const float* __restrict__ b,
                                float* __restrict__ o) {
  int i = blockIdx.x * blockDim.x + threadIdx.x;
  if (i < G4c) {
    const int g = i >> 9, u = i & 511;
    o[u * 4 + g] = a[i] + b[i];
  }
}

__global__ void cvt4_k(const float* __restrict__ x, ushort* __restrict__ y, int n4) {
  int i = blockIdx.x * 256 + threadIdx.x;
  if (i < n4) {
    float4 v = ((const float4*)x)[i];
    ushort4 o; o.x = f2bf(v.x); o.y = f2bf(v.y); o.z = f2bf(v.z); o.w = f2bf(v.w);
    ((ushort4*)y)[i] = o;
  }
}

// W_ih -> bf16 with rows permuted: out row r' = u*4+g  <-  W_ih row g*512+u
__global__ __launch_bounds__(256) void cvt_wih_perm_k(
    const float* __restrict__ W, ushort* __restrict__ out)
{
  const int rp = blockIdx.x;            // 0..2047
  const int u = rp >> 2, g = rp & 3;
  const float* src = W + (size_t)(g * 512 + u) * 512;
  ushort* dst = out + (size_t)rp * 512;
  for (int k = threadIdx.x; k < 512; k += 256) dst[k] = f2bf(src[k]);
}

// W_hh -> bf16 MFMA-A-fragment order.
// thread idx = ((sw*16 + kf)*64 + lane); sw = slice*8 + wave.
// m = lane&15: u = (sw>>3)*32 + (sw&7)*4 + (m>>2), gate = m&3.
// k = kf*32 + (lane>>4)*8 + j, j=0..7.
__global__ __launch_bounds__(256) void cvt_whh_frag_k(
    const float* __restrict__ Whh, ushort* __restrict__ out)
{
  const int idx = blockIdx.x * 256 + threadIdx.x;   // 512 blocks -> 131072
  const int lane = idx & 63;
  const int kf = (idx >> 6) & 15;
  const int sw = idx >> 10;
  const int m = lane & 15;
  const int u = (sw >> 3) * 32 + (sw & 7) * 4 + (m >> 2);
  const int gate = m & 3;
  const int k0 = kf * 32 + (lane >> 4) * 8;
  const float* src = Whh + ((size_t)(gate * RHc + u)) * RHc + k0;
  ushort4 o0, o1;
  o0.x = f2bf(src[0]); o0.y = f2bf(src[1]); o0.z = f2bf(src[2]); o0.w = f2bf(src[3]);
  o1.x = f2bf(src[4]); o1.y = f2bf(src[5]); o1.z = f2bf(src[6]); o1.w = f2bf(src[7]);
  ushort* dst = out + (size_t)idx * 8;
  *(ushort4*)dst = o0;
  *(ushort4*)(dst + 4) = o1;
}

// ---------------- bf16 MFMA GEMM: C = act(A @ Wb^T + bias) ----------------
__global__ __launch_bounds__(256) void bgemm_bt(
    const void* __restrict__ Aptr, const ushort* __restrict__ Wb,
    const float* __restrict__ bias, void* __restrict__ Cptr,
    int M, int N, int K, int amode, int outMode,
    const float* __restrict__ utt, const float* __restrict__ xo, int trow0)
{
  __shared__ ushort As[128 * 40];
  __shared__ ushort Ws[128 * 40];
  const int tid = threadIdx.x;
  const int lane = tid & 63, wid = tid >> 6;
  const int wm = wid >> 1, wn = wid & 1;
  const int row0 = blockIdx.y * 128, col0 = blockIdx.x * 128;

  f32x4 acc[4][4];
#pragma unroll
  for (int i = 0; i < 4; ++i)
#pragma unroll
    for (int j = 0; j < 4; ++j) {
      f32x4 z = {0.f, 0.f, 0.f, 0.f};
      acc[i][j] = z;
    }

  const int r = tid >> 1, kq = (tid & 1) * 16;

  for (int kb = 0; kb < K; kb += 32) {
    const int k = kb + kq;
    if (amode == 2) {
      const ushort* ap = (const ushort*)Aptr + (size_t)(row0 + r) * K + k;
      *(uint4*)&As[r * 40 + kq] = *(const uint4*)ap;
      *(uint4*)&As[r * 40 + kq + 8] = *(const uint4*)(ap + 8);
    } else {
      const float* ap;
      if (amode == 0) {
        ap = (const float*)Aptr + (size_t)(row0 + r) * K + k;
      } else {
        const int b = r;
        const int t = trow0 + blockIdx.y;
        ap = (k < Hc) ? utt + ((size_t)b * Tc + t) * Hc + k
                      : xo + (size_t)b * Hc + (k - Hc);
      }
      const float4 f0 = *(const float4*)ap;
      const float4 f1 = *(const float4*)(ap + 4);
      const float4 f2 = *(const float4*)(ap + 8);
      const float4 f3 = *(const float4*)(ap + 12);
      uint4 u0, u1;
      u0.x = pack2(f0.x, f0.y); u0.y = pack2(f0.z, f0.w);
      u0.z = pack2(f1.x, f1.y); u0.w = pack2(f1.z, f1.w);
      u1.x = pack2(f2.x, f2.y); u1.y = pack2(f2.z, f2.w);
      u1.z = pack2(f3.x, f3.y); u1.w = pack2(f3.z, f3.w);
      *(uint4*)&As[r * 40 + kq] = u0;
      *(uint4*)&As[r * 40 + kq + 8] = u1;
    }
    {
      const ushort* wp = Wb + (size_t)(col0 + r) * K + k;
      *(uint4*)&Ws[r * 40 + kq] = *(const uint4*)wp;
      *(uint4*)&Ws[r * 40 + kq + 8] = *(const uint4*)(wp + 8);
    }
    __syncthreads();
    const int koff = (lane >> 4) * 8;
    const int ar = wm * 64 + (lane & 15);
    const int wr = wn * 64 + (lane & 15);
    bf16x8 af[4], wf[4];
#pragma unroll
    for (int i = 0; i < 4; ++i) af[i] = *(const bf16x8*)&As[(ar + i * 16) * 40 + koff];
#pragma unroll
    for (int i = 0; i < 4; ++i) wf[i] = *(const bf16x8*)&Ws[(wr + i * 16) * 40 + koff];
#pragma unroll
    for (int fm = 0; fm < 4; ++fm)
#pragma unroll
      for (int fn = 0; fn < 4; ++fn)
        acc[fm][fn] = __builtin_amdgcn_mfma_f32_16x16x32_bf16(af[fm], wf[fn], acc[fm][fn], 0, 0, 0);
    __syncthreads();
  }

#pragma unroll
  for (int fm = 0; fm < 4; ++fm) {
    const int m0 = row0 + wm * 64 + fm * 16 + ((lane >> 4) * 4);
#pragma unroll
    for (int fn = 0; fn < 4; ++fn) {
      const int n = col0 + wn * 64 + fn * 16 + (lane & 15);
      const float bb = bias[n];
#pragma unroll
      for (int q = 0; q < 4; ++q) {
        const float v = acc[fm][fn][q] + bb;
        if (outMode == 1)
          ((ushort*)Cptr)[(size_t)(m0 + q) * N + n] = f2bf(sigmoidf_(v));
        else
          ((float*)Cptr)[(size_t)(m0 + q) * N + n] = v;
      }
    }
  }
}

// ------------- attention: fold q and P per (b,h); 1536 blocks -------------
__global__ __launch_bounds__(256) void fold_qp_k(
    const float* __restrict__ slot, const float* __restrict__ Wq,
    const float* __restrict__ bq, const float* __restrict__ Wk,
    const float* __restrict__ bk, ushort* __restrict__ Pb, float* __restrict__ cqB)
{
  __shared__ float ss[Hc];
  __shared__ float qp[4][DKc];
  __shared__ float qs[DKc];
  const int bx = blockIdx.x;
  const int b = bx / NHEAD, h = bx % NHEAD;
  const int tid = threadIdx.x;
  for (int i = tid; i < Hc; i += 256) ss[i] = slot[(size_t)b * Hc + i];
  __syncthreads();
  {
    const int d = tid & 63, qt = tid >> 6;
    const float* wr = Wq + (size_t)(h * DKc + d) * Hc + qt * 192;
    const float* sb = ss + qt * 192;
    float a = 0.f;
    for (int e = 0; e < 192; e += 4) {
      const float4 wv = *(const float4*)(wr + e);
      a += wv.x * sb[e] + wv.y * sb[e + 1] + wv.z * sb[e + 2] + wv.w * sb[e + 3];
    }
    qp[qt][d] = a;
  }
  __syncthreads();
  if (tid < DKc)
    qs[tid] = qp[0][tid] + qp[1][tid] + qp[2][tid] + qp[3][tid] + bq[h * DKc + tid];
  __syncthreads();
  if (tid < DKc) {
    float pv = qs[tid] * bk[h * DKc + tid];
#pragma unroll
    for (int off = 32; off; off >>= 1) pv += __shfl_xor(pv, off);
    if (tid == 0) cqB[b * NHEAD + h] = pv;
  }
  for (int j = tid; j < Hc; j += 256) {
    float a = 0.f;
#pragma unroll 8
    for (int d = 0; d < DKc; ++d)
      a = fmaf(qs[d], Wk[(size_t)(h * DKc + d) * Hc + j], a);
    Pb[((size_t)b * NHEAD + h) * Hc + j] = f2bf(a);
  }
}

// per-b scores + wave-shuffle softmax
__global__ __launch_bounds__(256) void attn_scores2_k(
    const ushort* __restrict__ Pb, const float* __restrict__ cqB,
    const float* __restrict__ utt, float* __restrict__ Att)
{
  __shared__ float Phs[NHEAD][Hc];
  __shared__ float sc[NHEAD][Tc];
  const int b = blockIdx.x;
  const int tid = threadIdx.x;
  for (int i = tid; i < NHEAD * Hc; i += 256)
    ((float*)Phs)[i] = bf2f(Pb[(size_t)b * NHEAD * Hc + i]);
  __syncthreads();
  const int t = tid & 127, hh = tid >> 7;
  const int h0 = hh * 6;
  float a6[6];
#pragma unroll
  for (int i = 0; i < 6; ++i) a6[i] = 0.f;
  const float* xr = utt + ((size_t)b * Tc + t) * Hc;
  for (int j = 0; j < Hc; j += 4) {
    const float4 xv = *(const float4*)(xr + j);
#pragma unroll
    for (int i = 0; i < 6; ++i) {
      a6[i] = fmaf(xv.x, Phs[h0 + i][j], a6[i]);
      a6[i] = fmaf(xv.y, Phs[h0 + i][j + 1], a6[i]);
      a6[i] = fmaf(xv.z, Phs[h0 + i][j + 2], a6[i]);
      a6[i] = fmaf(xv.w, Phs[h0 + i][j + 3], a6[i]);
    }
  }
#pragma unroll
  for (int i = 0; i < 6; ++i)
    sc[h0 + i][t] = (a6[i] + cqB[b * NHEAD + h0 + i]) * 0.125f;
  __syncthreads();
  const int w = tid >> 6, lane = tid & 63;
#pragma unroll
  for (int i = 0; i < 3; ++i) {
    const int h = w * 3 + i;
    const float s0 = sc[h][lane], s1 = sc[h][lane + 64];
    float m = fmaxf(s0, s1);
#pragma unroll
    for (int off = 32; off; off >>= 1) m = fmaxf(m, __shfl_xor(m, off));
    const float e0 = expf(s0 - m), e1 = expf(s1 - m);
    float s = e0 + e1;
#pragma unroll
    for (int off = 32; off; off >>= 1) s += __shfl_xor(s, off);
    const float inv = 1.f / s;
    Att[((size_t)b * NHEAD + h) * Tc + lane] = e0 * inv;
    Att[((size_t)b * NHEAD + h) * Tc + lane + 64] = e1 * inv;
  }
}

// block per b, 256 threads: U (LDS) = sum_t Att*utt; Xc = Wv.U + bv
__global__ __launch_bounds__(256) void attn_uxc_k(
    const float* __restrict__ Att, const float* __restrict__ utt,
    const float* __restrict__ Wv, const float* __restrict__ bv,
    float* __restrict__ Xc)
{
  __shared__ float As[NHEAD][Tc];
  __shared__ float Us[NHEAD * Hc];
  const int b = blockIdx.x;
  const int tid = threadIdx.x;
  for (int i = tid; i < NHEAD * Tc; i += 256)
    ((float*)As)[i] = Att[(size_t)b * NHEAD * Tc + i];
  __syncthreads();
  float acc[NHEAD][3];
#pragma unroll
  for (int h = 0; h < NHEAD; ++h)
#pragma unroll
    for (int q = 0; q < 3; ++q) acc[h][q] = 0.f;
  for (int t = 0; t < Tc; ++t) {
    const float* xr = utt + ((size_t)b * Tc + t) * Hc;
    const float x0 = xr[tid], x1 = xr[tid + 256], x2 = xr[tid + 512];
#pragma unroll
    for (int h = 0; h < NHEAD; ++h) {
      const float a = As[h][t];
      acc[h][0] = fmaf(a, x0, acc[h][0]);
      acc[h][1] = fmaf(a, x1, acc[h][1]);
      acc[h][2] = fmaf(a, x2, acc[h][2]);
    }
  }
#pragma unroll
  for (int h = 0; h < NHEAD; ++h)
#pragma unroll
    for (int q = 0; q < 3; ++q)
      Us[h * Hc + tid + q * 256] = acc[h][q];
  __syncthreads();
#pragma unroll
  for (int rr = 0; rr < 3; ++rr) {
    const int hd = tid + rr * 256;
    const int h = hd >> 6;
    const float* wr = Wv + (size_t)hd * Hc;
    const float* ub = Us + h * Hc;
    float a = 0.f;
    for (int j = 0; j < Hc; j += 4) {
      const float4 w4 = *(const float4*)(wr + j);
      a += w4.x * ub[j] + w4.y * ub[j + 1] + w4.z * ub[j + 2] + w4.w * ub[j + 3];
    }
    Xc[(size_t)b * Hc + hd] = a + bv[hd];
  }
}

// MFMA LSTM with monotonic per-producer flag sync (no central barrier).
// 128 blocks = 8 groups (16 b) x 16 slices (32 u); gid = blk&7 -> XCD co-location.
// Wave = one 16x16 tile: rows = 4u x 4gates, cols = 16 b. A-frags in registers.
// flags[gid][sid] = t+1 after block (gid,sid) finished writing h(t). Monotonic
// across the whole call (chunk boundaries line up; memset 0 matches t0=0).
__global__ __launch_bounds__(512, 1) void lstm_mfma_k(
    const ushort* __restrict__ WhhF, const float* __restrict__ GXc,
    ushort* __restrict__ hbuf, float* __restrict__ Hch,
    float* __restrict__ Cb, int t0, int nsteps, unsigned* __restrict__ bars)
{
  const int blk = blockIdx.x;
  const int gid = blk & 7, sid = blk >> 3;
  const int tid = threadIdx.x;
  const int w = tid >> 6, lane = tid & 63;
  const int bl = lane & 15, uq = lane >> 4;
  const int uglob = sid * 32 + w * 4 + uq;
  const int bglob = gid * 16 + bl;
  unsigned* flags = bars + gid * 16;   // one 64B line per group

  // A fragments: register-resident for the whole launch
  bf16x8 afr[16];
  {
    const ushort* base = WhhF + ((size_t)((sid * 8 + w) * 16) * 64 + lane) * 8;
#pragma unroll
    for (int kf = 0; kf < 16; ++kf)
      afr[kf] = *(const bf16x8*)(base + (size_t)kf * 64 * 8);
  }

  float creg = (t0 > 0) ? Cb[(size_t)bglob * RHc + uglob] : 0.f;
  ushort* hbg = hbuf + (size_t)gid * (2 * 16 * RHc);

  float4 gx4 = *(const float4*)(GXc + ((size_t)0 * Bc + bglob) * G4c + uglob * 4);

  for (int s = 0; s < nsteps; ++s) {
    const int t = t0 + s;
    f32x4 acc = {0.f, 0.f, 0.f, 0.f};
    if (t > 0) {
      // wait: every producer in my group must have published h(t-1)
      if (s > 0) {
        if (lane < 16) {
          while (__hip_atomic_load(&flags[lane], __ATOMIC_RELAXED,
                                   __HIP_MEMORY_SCOPE_AGENT) < (unsigned)t)
            __builtin_amdgcn_s_sleep(1);
        }
        __builtin_amdgcn_fence(__ATOMIC_ACQUIRE, "agent");
      }
      const ushort* hsrc = hbg + (size_t)((t & 1) ^ 1) * (16 * RHc) + (size_t)bl * RHc + uq * 8;
#pragma unroll
      for (int kf = 0; kf < 16; ++kf) {
        const bf16x8 bf = *(const bf16x8*)(hsrc + kf * 32);
        acc = __builtin_amdgcn_mfma_f32_16x16x32_bf16(afr[kf], bf, acc, 0, 0, 0);
      }
    }
    // epilogue: lane owns (u=uglob, b=bglob); acc[q] = gate q (i,f,g,o)
    const float gi = gx4.x + acc[0];
    const float gf = gx4.y + acc[1];
    const float gg = gx4.z + acc[2];
    const float go = gx4.w + acc[3];
    const float iv = sigmoidf_(gi);
    const float fv = sigmoidf_(gf);
    const float gv = tanhf(gg);
    const float ov = sigmoidf_(go);
    creg = fmaf(fv, creg, iv * gv);
    const float hval = ov * tanhf(creg);
    hbg[(size_t)(t & 1) * (16 * RHc) + (size_t)bl * RHc + uglob] = f2bf(hval);
    Hch[((size_t)s * Bc + bglob) * RHc + uglob] = hval;
    if (s != nsteps - 1) {
      // prefetch next step's GX (independent of h) before publish/wait
      gx4 = *(const float4*)(GXc + ((size_t)(s + 1) * Bc + bglob) * G4c + uglob * 4);
    }
    // publish: all block stores drained by syncthreads' vmcnt(0), then flag
    __syncthreads();
    if (tid == 0) {
      __builtin_amdgcn_fence(__ATOMIC_RELEASE, "agent");
      __hip_atomic_store(&flags[sid], (unsigned)(t + 1), __ATOMIC_RELAXED,
                         __HIP_MEMORY_SCOPE_AGENT);
    }
  }
  Cb[(size_t)bglob * RHc + uglob] = creg;
}

// one wave per (tl,b): y = h @ W_tag^T + b_tag, LayerNorm over NT=10
__global__ __launch_bounds__(256) void tag_ln_k(
    const float* __restrict__ Hch, const float* __restrict__ Wtag,
    const float* __restrict__ btag, const float* __restrict__ lng,
    const float* __restrict__ lnb, float* __restrict__ out, int t0)
{
  const int wid = (blockIdx.x * blockDim.x + threadIdx.x) >> 6;
  const int lane = threadIdx.x & 63;
  const int tl = wid >> 7, b = wid & 127;
  const int t = t0 + tl;
  const float* hp = Hch + ((size_t)tl * Bc + b) * RHc;
  float y[NTc];
#pragma unroll
  for (int j = 0; j < NTc; ++j) y[j] = 0.f;
  for (int k = lane; k < RHc; k += 64) {
    const float hv = hp[k];
#pragma unroll
    for (int j = 0; j < NTc; ++j)
      y[j] = fmaf(hv, Wtag[(size_t)j * RHc + k], y[j]);
  }
#pragma unroll
  for (int off = 32; off > 0; off >>= 1)
#pragma unroll
    for (int j = 0; j < NTc; ++j)
      y[j] += __shfl_xor(y[j], off);
  float mu = 0.f;
#pragma unroll
  for (int j = 0; j < NTc; ++j) { y[j] += btag[j]; mu += y[j]; }
  mu *= (1.0f / NTc);
  float var = 0.f;
#pragma unroll
  for (int j = 0; j < NTc; ++j) { const float d = y[j] - mu; var = fmaf(d, d, var); }
  var *= (1.0f / NTc);
  const float inv = rsqrtf(var + LNEPS);
  if (lane < NTc) {
    out[(size_t)b * NTc * Tc + (size_t)lane * Tc + t] =
        (y[lane] - mu) * inv * lng[lane] + lnb[lane];
  }
}

extern "C" void kernel_launch(void* const* d_in, const int* in_sizes, int n_in,
                              void* d_out, int out_size, void* d_ws, size_t ws_size,
                              hipStream_t stream)
{
  const float* slot = (const float*)d_in[0];
  const float* utt  = (const float*)d_in[1];
  const float* Wq = (const float*)d_in[2];   const float* bq = (const float*)d_in[3];
  const float* Wk = (const float*)d_in[4];   const float* bk = (const float*)d_in[5];
  const float* Wv = (const float*)d_in[6];   const float* bv = (const float*)d_in[7];
  const float* Wo = (const float*)d_in[8];   const float* bo = (const float*)d_in[9];
  const float* W_in = (const float*)d_in[10]; const float* b_in = (const float*)d_in[11];
  const float* W_ih = (const float*)d_in[12]; const float* W_hh = (const float*)d_in[13];
  const float* b_ih = (const float*)d_in[14]; const float* b_hh = (const float*)d_in[15];
  const float* W_tag = (const float*)d_in[16]; const float* b_tag = (const float*)d_in[17];
  const float* ln_g = (const float*)d_in[18]; const float* ln_b = (const float*)d_in[19];
  float* out = (float*)d_out;
  float* ws = (float*)d_ws;

  // adaptive chunk (floats): fixed = 2,265,088; per-chunk = 360,448
  int CHT = 16;
  while (CHT > 2 && 4ull * (2265088ull + 360448ull * (unsigned)CHT) > ws_size)
    CHT >>= 1;
  const int NCH = Tc / CHT;

  float* Xc    = ws;                          // 98304
  float* Xo    = Xc + 98304;                  // 98304
  float* bsum  = Xo + 98304;                  // 2048
  float* Cb    = bsum + 2048;                 // 65536
  float* Att   = Cb + 65536;                  // 196608
  ushort* hbuf = (ushort*)(Att + 196608);     // 131072 us (65536 f)
  ushort* WinB = (ushort*)(ws + 526336);      // 786432 us (393216 f)
  ushort* WihB = (ushort*)(ws + 919552);      // 1048576 us (524288 f)
  ushort* WoB  = (ushort*)(ws + 1443840);     // 589824 us (294912 f)
  ushort* WhhF = (ushort*)(ws + 1738752);     // 1048576 us (524288 f)
  float* cqB   = ws + 2263040;                // 1536
  unsigned* bars = (unsigned*)(ws + 2264576); // 512 u32 (8 grp x 16 flags used)
  // loop region: LINc bf16, GXc f32, Hch f32; Pb overlays it (pre-loop only)
  ushort* LINc = (ushort*)(ws + 2265088);                    // 65536*CHT us
  float* GXc   = ws + 2265088 + (size_t)32768 * CHT;         // 262144*CHT f
  float* Hch   = GXc + (size_t)262144 * CHT;                 // 65536*CHT f
  ushort* Pb   = (ushort*)(ws + 2265088);                    // overlay

  (void)hipMemsetAsync(bars, 0, 2048, stream);

  // weight conversions + bias sum (W_ih rows permuted to gate-interleaved)
  hipLaunchKernelGGL(cvt4_k, dim3(768), dim3(256), 0, stream, W_in, WinB, 196608);
  hipLaunchKernelGGL(cvt_wih_perm_k, dim3(2048), dim3(256), 0, stream, W_ih, WihB);
  hipLaunchKernelGGL(cvt4_k, dim3(576), dim3(256), 0, stream, Wo, WoB, 147456);
  hipLaunchKernelGGL(cvt_whh_frag_k, dim3(512), dim3(256), 0, stream, W_hh, WhhF);
  hipLaunchKernelGGL(bias_sum_perm_k, dim3(8), dim3(256), 0, stream, b_ih, b_hh, bsum);

  // attention
  hipLaunchKernelGGL(fold_qp_k, dim3(Bc * NHEAD), dim3(256), 0, stream,
                     slot, Wq, bq, Wk, bk, Pb, cqB);
  hipLaunchKernelGGL(attn_scores2_k, dim3(Bc), dim3(256), 0, stream, Pb, cqB, utt, Att);
  hipLaunchKernelGGL(attn_uxc_k, dim3(Bc), dim3(256), 0, stream, Att, utt, Wv, bv, Xc);
  hipLaunchKernelGGL(bgemm_bt, dim3(6, 1), dim3(256), 0, stream,
                     (const void*)Xc, WoB, bo, (void*)Xo, 128, 768, 768, 0, 0,
                     (const float*)nullptr, (const float*)nullptr, 0);

  // chunked precompute + MFMA LSTM + chunked tag/LN
  for (int tc = 0; tc < NCH; ++tc) {
    hipLaunchKernelGGL(bgemm_bt, dim3(4, CHT), dim3(256), 0, stream,
                       (const void*)nullptr, WinB, b_in, (void*)LINc,
                       CHT * Bc, 512, 1536, 1, 1, utt, Xo, tc * CHT);
    hipLaunchKernelGGL(bgemm_bt, dim3(16, CHT), dim3(256), 0, stream,
                       (const void*)LINc, WihB, bsum, (void*)GXc,
                       CHT * Bc, 2048, 512, 2, 0,
                       (const float*)nullptr, (const float*)nullptr, 0);
    hipLaunchKernelGGL(lstm_mfma_k, dim3(128), dim3(512), 0, stream,
                       WhhF, GXc, hbuf, Hch, Cb, tc * CHT, CHT, bars);
    hipLaunchKernelGGL(tag_ln_k, dim3(CHT * 32), dim3(256), 0, stream,
                       Hch, W_tag, b_tag, ln_g, ln_b, out, tc * CHT);
  }
}

// Round 11
// 2122.756 us; speedup vs baseline: 1.4972x; 1.4972x over previous
//
#include <hip/hip_runtime.h>
#include <hip/hip_bf16.h>
#include <math.h>

#define Bc 128
#define Tc 128
#define Hc 768
#define NHEAD 12
#define DKc 64
#define RHc 512
#define G4c 2048
#define NTc 10
#define LNEPS 1e-5f
#define NSLC 8    // blocks per LSTM group

typedef short bf16x8 __attribute__((ext_vector_type(8)));
typedef float f32x4 __attribute__((ext_vector_type(4)));

__device__ __forceinline__ float sigmoidf_(float x) { return 1.0f / (1.0f + __expf(-x)); }
__device__ __forceinline__ float tanhf_(float x) { return 1.0f - 2.0f / (__expf(2.0f * x) + 1.0f); }

__device__ __forceinline__ ushort f2bf(float f) {
  union { float f; uint u; } c; c.f = f;
  uint r = (c.u + 0x7FFFu + ((c.u >> 16) & 1u)) >> 16;
  return (ushort)r;
}
__device__ __forceinline__ float bf2f(ushort u) {
  union { uint u; float f; } c; c.u = ((uint)u) << 16;
  return c.f;
}
__device__ __forceinline__ uint pack2(float a, float b) {
  return (uint)f2bf(a) | ((uint)f2bf(b) << 16);
}

// bsum permuted to gate-interleaved order: out[u*4+g] = b_ih[g*512+u] + b_hh[g*512+u]
__global__ void bias_sum_perm_k(const float* __restrict__ a, const float* __restrict__ b,
                                float* __restrict__ o) {
  int i = blockIdx.x * blockDim.x + threadIdx.x;
  if (i < G4c) {
    const int g = i >> 9, u = i & 511;
    o[u * 4 + g] = a[i] + b[i];
  }
}

__global__ void cvt4_k(const float* __restrict__ x, ushort* __restrict__ y, int n4) {
  int i = blockIdx.x * 256 + threadIdx.x;
  if (i < n4) {
    float4 v = ((const float4*)x)[i];
    ushort4 o; o.x = f2bf(v.x); o.y = f2bf(v.y); o.z = f2bf(v.z); o.w = f2bf(v.w);
    ((ushort4*)y)[i] = o;
  }
}

// W_ih -> bf16 with rows permuted: out row r' = u*4+g  <-  W_ih row g*512+u
__global__ __launch_bounds__(256) void cvt_wih_perm_k(
    const float* __restrict__ W, ushort* __restrict__ out)
{
  const int rp = blockIdx.x;            // 0..2047
  const int u = rp >> 2, g = rp & 3;
  const float* src = W + (size_t)(g * 512 + u) * 512;
  ushort* dst = out + (size_t)rp * 512;
  for (int k = threadIdx.x; k < 512; k += 256) dst[k] = f2bf(src[k]);
}

// W_hh -> bf16 MFMA-A-fragment order.
// tile index ti (0..127): u = (ti>>3)*32 + (ti&7)*4 + (m>>2), gate = m&3,
// k = kf*32 + (lane>>4)*8 + j. Stored as [(ti*16+kf)*64 + lane]*8.
__global__ __launch_bounds__(256) void cvt_whh_frag_k(
    const float* __restrict__ Whh, ushort* __restrict__ out)
{
  const int idx = blockIdx.x * 256 + threadIdx.x;   // 512 blocks -> 131072
  const int lane = idx & 63;
  const int kf = (idx >> 6) & 15;
  const int ti = idx >> 10;
  const int m = lane & 15;
  const int u = (ti >> 3) * 32 + (ti & 7) * 4 + (m >> 2);
  const int gate = m & 3;
  const int k0 = kf * 32 + (lane >> 4) * 8;
  const float* src = Whh + ((size_t)(gate * RHc + u)) * RHc + k0;
  ushort4 o0, o1;
  o0.x = f2bf(src[0]); o0.y = f2bf(src[1]); o0.z = f2bf(src[2]); o0.w = f2bf(src[3]);
  o1.x = f2bf(src[4]); o1.y = f2bf(src[5]); o1.z = f2bf(src[6]); o1.w = f2bf(src[7]);
  ushort* dst = out + (size_t)idx * 8;
  *(ushort4*)dst = o0;
  *(ushort4*)(dst + 4) = o1;
}

// ---------------- bf16 MFMA GEMM: C = act(A @ Wb^T + bias) ----------------
__global__ __launch_bounds__(256) void bgemm_bt(
    const void* __restrict__ Aptr, const ushort* __restrict__ Wb,
    const float* __restrict__ bias, void* __restrict__ Cptr,
    int M, int N, int K, int amode, int outMode,
    const float* __restrict__ utt, const float* __restrict__ xo, int trow0)
{
  __shared__ ushort As[128 * 40];
  __shared__ ushort Ws[128 * 40];
  const int tid = threadIdx.x;
  const int lane = tid & 63, wid = tid >> 6;
  const int wm = wid >> 1, wn = wid & 1;
  const int row0 = blockIdx.y * 128, col0 = blockIdx.x * 128;

  f32x4 acc[4][4];
#pragma unroll
  for (int i = 0; i < 4; ++i)
#pragma unroll
    for (int j = 0; j < 4; ++j) {
      f32x4 z = {0.f, 0.f, 0.f, 0.f};
      acc[i][j] = z;
    }

  const int r = tid >> 1, kq = (tid & 1) * 16;

  for (int kb = 0; kb < K; kb += 32) {
    const int k = kb + kq;
    if (amode == 2) {
      const ushort* ap = (const ushort*)Aptr + (size_t)(row0 + r) * K + k;
      *(uint4*)&As[r * 40 + kq] = *(const uint4*)ap;
      *(uint4*)&As[r * 40 + kq + 8] = *(const uint4*)(ap + 8);
    } else {
      const float* ap;
      if (amode == 0) {
        ap = (const float*)Aptr + (size_t)(row0 + r) * K + k;
      } else {
        const int b = r;
        const int t = trow0 + blockIdx.y;
        ap = (k < Hc) ? utt + ((size_t)b * Tc + t) * Hc + k
                      : xo + (size_t)b * Hc + (k - Hc);
      }
      const float4 f0 = *(const float4*)ap;
      const float4 f1 = *(const float4*)(ap + 4);
      const float4 f2 = *(const float4*)(ap + 8);
      const float4 f3 = *(const float4*)(ap + 12);
      uint4 u0, u1;
      u0.x = pack2(f0.x, f0.y); u0.y = pack2(f0.z, f0.w);
      u0.z = pack2(f1.x, f1.y); u0.w = pack2(f1.z, f1.w);
      u1.x = pack2(f2.x, f2.y); u1.y = pack2(f2.z, f2.w);
      u1.z = pack2(f3.x, f3.y); u1.w = pack2(f3.z, f3.w);
      *(uint4*)&As[r * 40 + kq] = u0;
      *(uint4*)&As[r * 40 + kq + 8] = u1;
    }
    {
      const ushort* wp = Wb + (size_t)(col0 + r) * K + k;
      *(uint4*)&Ws[r * 40 + kq] = *(const uint4*)wp;
      *(uint4*)&Ws[r * 40 + kq + 8] = *(const uint4*)(wp + 8);
    }
    __syncthreads();
    const int koff = (lane >> 4) * 8;
    const int ar = wm * 64 + (lane & 15);
    const int wr = wn * 64 + (lane & 15);
    bf16x8 af[4], wf[4];
#pragma unroll
    for (int i = 0; i < 4; ++i) af[i] = *(const bf16x8*)&As[(ar + i * 16) * 40 + koff];
#pragma unroll
    for (int i = 0; i < 4; ++i) wf[i] = *(const bf16x8*)&Ws[(wr + i * 16) * 40 + koff];
#pragma unroll
    for (int fm = 0; fm < 4; ++fm)
#pragma unroll
      for (int fn = 0; fn < 4; ++fn)
        acc[fm][fn] = __builtin_amdgcn_mfma_f32_16x16x32_bf16(af[fm], wf[fn], acc[fm][fn], 0, 0, 0);
    __syncthreads();
  }

#pragma unroll
  for (int fm = 0; fm < 4; ++fm) {
    const int m0 = row0 + wm * 64 + fm * 16 + ((lane >> 4) * 4);
#pragma unroll
    for (int fn = 0; fn < 4; ++fn) {
      const int n = col0 + wn * 64 + fn * 16 + (lane & 15);
      const float bb = bias[n];
#pragma unroll
      for (int q = 0; q < 4; ++q) {
        const float v = acc[fm][fn][q] + bb;
        if (outMode == 1)
          ((ushort*)Cptr)[(size_t)(m0 + q) * N + n] = f2bf(sigmoidf_(v));
        else
          ((float*)Cptr)[(size_t)(m0 + q) * N + n] = v;
      }
    }
  }
}

// ------------- attention: fold q and P per (b,h); 1536 blocks -------------
__global__ __launch_bounds__(256) void fold_qp_k(
    const float* __restrict__ slot, const float* __restrict__ Wq,
    const float* __restrict__ bq, const float* __restrict__ Wk,
    const float* __restrict__ bk, ushort* __restrict__ Pb, float* __restrict__ cqB)
{
  __shared__ float ss[Hc];
  __shared__ float qp[4][DKc];
  __shared__ float qs[DKc];
  const int bx = blockIdx.x;
  const int b = bx / NHEAD, h = bx % NHEAD;
  const int tid = threadIdx.x;
  for (int i = tid; i < Hc; i += 256) ss[i] = slot[(size_t)b * Hc + i];
  __syncthreads();
  {
    const int d = tid & 63, qt = tid >> 6;
    const float* wr = Wq + (size_t)(h * DKc + d) * Hc + qt * 192;
    const float* sb = ss + qt * 192;
    float a = 0.f;
    for (int e = 0; e < 192; e += 4) {
      const float4 wv = *(const float4*)(wr + e);
      a += wv.x * sb[e] + wv.y * sb[e + 1] + wv.z * sb[e + 2] + wv.w * sb[e + 3];
    }
    qp[qt][d] = a;
  }
  __syncthreads();
  if (tid < DKc)
    qs[tid] = qp[0][tid] + qp[1][tid] + qp[2][tid] + qp[3][tid] + bq[h * DKc + tid];
  __syncthreads();
  if (tid < DKc) {
    float pv = qs[tid] * bk[h * DKc + tid];
#pragma unroll
    for (int off = 32; off; off >>= 1) pv += __shfl_xor(pv, off);
    if (tid == 0) cqB[b * NHEAD + h] = pv;
  }
  for (int j = tid; j < Hc; j += 256) {
    float a = 0.f;
#pragma unroll 8
    for (int d = 0; d < DKc; ++d)
      a = fmaf(qs[d], Wk[(size_t)(h * DKc + d) * Hc + j], a);
    Pb[((size_t)b * NHEAD + h) * Hc + j] = f2bf(a);
  }
}

// per-b scores + wave-shuffle softmax
__global__ __launch_bounds__(256) void attn_scores2_k(
    const ushort* __restrict__ Pb, const float* __restrict__ cqB,
    const float* __restrict__ utt, float* __restrict__ Att)
{
  __shared__ float Phs[NHEAD][Hc];
  __shared__ float sc[NHEAD][Tc];
  const int b = blockIdx.x;
  const int tid = threadIdx.x;
  for (int i = tid; i < NHEAD * Hc; i += 256)
    ((float*)Phs)[i] = bf2f(Pb[(size_t)b * NHEAD * Hc + i]);
  __syncthreads();
  const int t = tid & 127, hh = tid >> 7;
  const int h0 = hh * 6;
  float a6[6];
#pragma unroll
  for (int i = 0; i < 6; ++i) a6[i] = 0.f;
  const float* xr = utt + ((size_t)b * Tc + t) * Hc;
  for (int j = 0; j < Hc; j += 4) {
    const float4 xv = *(const float4*)(xr + j);
#pragma unroll
    for (int i = 0; i < 6; ++i) {
      a6[i] = fmaf(xv.x, Phs[h0 + i][j], a6[i]);
      a6[i] = fmaf(xv.y, Phs[h0 + i][j + 1], a6[i]);
      a6[i] = fmaf(xv.z, Phs[h0 + i][j + 2], a6[i]);
      a6[i] = fmaf(xv.w, Phs[h0 + i][j + 3], a6[i]);
    }
  }
#pragma unroll
  for (int i = 0; i < 6; ++i)
    sc[h0 + i][t] = (a6[i] + cqB[b * NHEAD + h0 + i]) * 0.125f;
  __syncthreads();
  const int w = tid >> 6, lane = tid & 63;
#pragma unroll
  for (int i = 0; i < 3; ++i) {
    const int h = w * 3 + i;
    const float s0 = sc[h][lane], s1 = sc[h][lane + 64];
    float m = fmaxf(s0, s1);
#pragma unroll
    for (int off = 32; off; off >>= 1) m = fmaxf(m, __shfl_xor(m, off));
    const float e0 = expf(s0 - m), e1 = expf(s1 - m);
    float s = e0 + e1;
#pragma unroll
    for (int off = 32; off; off >>= 1) s += __shfl_xor(s, off);
    const float inv = 1.f / s;
    Att[((size_t)b * NHEAD + h) * Tc + lane] = e0 * inv;
    Att[((size_t)b * NHEAD + h) * Tc + lane + 64] = e1 * inv;
  }
}

// block per b, 256 threads: U (LDS) = sum_t Att*utt; Xc = Wv.U + bv
__global__ __launch_bounds__(256) void attn_uxc_k(
    const float* __restrict__ Att, const float* __restrict__ utt,
    const float* __restrict__ Wv, const float* __restrict__ bv,
    float* __restrict__ Xc)
{
  __shared__ float As[NHEAD][Tc];
  __shared__ float Us[NHEAD * Hc];
  const int b = blockIdx.x;
  const int tid = threadIdx.x;
  for (int i = tid; i < NHEAD * Tc; i += 256)
    ((float*)As)[i] = Att[(size_t)b * NHEAD * Tc + i];
  __syncthreads();
  float acc[NHEAD][3];
#pragma unroll
  for (int h = 0; h < NHEAD; ++h)
#pragma unroll
    for (int q = 0; q < 3; ++q) acc[h][q] = 0.f;
  for (int t = 0; t < Tc; ++t) {
    const float* xr = utt + ((size_t)b * Tc + t) * Hc;
    const float x0 = xr[tid], x1 = xr[tid + 256], x2 = xr[tid + 512];
#pragma unroll
    for (int h = 0; h < NHEAD; ++h) {
      const float a = As[h][t];
      acc[h][0] = fmaf(a, x0, acc[h][0]);
      acc[h][1] = fmaf(a, x1, acc[h][1]);
      acc[h][2] = fmaf(a, x2, acc[h][2]);
    }
  }
#pragma unroll
  for (int h = 0; h < NHEAD; ++h)
#pragma unroll
    for (int q = 0; q < 3; ++q)
      Us[h * Hc + tid + q * 256] = acc[h][q];
  __syncthreads();
#pragma unroll
  for (int rr = 0; rr < 3; ++rr) {
    const int hd = tid + rr * 256;
    const int h = hd >> 6;
    const float* wr = Wv + (size_t)hd * Hc;
    const float* ub = Us + h * Hc;
    float a = 0.f;
    for (int j = 0; j < Hc; j += 4) {
      const float4 w4 = *(const float4*)(wr + j);
      a += w4.x * ub[j] + w4.y * ub[j + 1] + w4.z * ub[j + 2] + w4.w * ub[j + 3];
    }
    Xc[(size_t)b * Hc + hd] = a + bv[hd];
  }
}

// -------- per-group barrier: NSLC blocks, private 128B line (round-9 proven) --------
__device__ __forceinline__ void group_barrier(unsigned* line) {
  __syncthreads();
  if (threadIdx.x == 0) {
    __builtin_amdgcn_fence(__ATOMIC_RELEASE, "agent");
    unsigned g = __hip_atomic_load(line + 1, __ATOMIC_RELAXED, __HIP_MEMORY_SCOPE_AGENT);
    unsigned a = __hip_atomic_fetch_add(line, 1u, __ATOMIC_ACQ_REL, __HIP_MEMORY_SCOPE_AGENT);
    if (a == NSLC - 1) {
      __hip_atomic_store(line, 0u, __ATOMIC_RELAXED, __HIP_MEMORY_SCOPE_AGENT);
      __hip_atomic_store(line + 1, g + 1u, __ATOMIC_RELEASE, __HIP_MEMORY_SCOPE_AGENT);
    } else {
      while (__hip_atomic_load(line + 1, __ATOMIC_RELAXED, __HIP_MEMORY_SCOPE_AGENT) == g)
        __builtin_amdgcn_s_sleep(1);
      __builtin_amdgcn_fence(__ATOMIC_ACQUIRE, "agent");
    }
  }
  __syncthreads();
}

// MFMA LSTM: 64 blocks = 8 groups (16 b) x 8 slices (64 u); gid = blk&7 -> XCD co-locate.
// Wave = TWO 16x16 tiles (8u x 4g x 16b); A-frags register-resident (2x16x4 VGPR).
// B-frag shared across both tiles. h ping-pong in global, barrier = 8 participants.
__global__ __launch_bounds__(512, 1) void lstm_mfma_k(
    const ushort* __restrict__ WhhF, const float* __restrict__ GXc,
    ushort* __restrict__ hbuf, float* __restrict__ Hch,
    float* __restrict__ Cb, int t0, int nsteps, unsigned* __restrict__ bars)
{
  const int blk = blockIdx.x;
  const int gid = blk & 7, sid = blk >> 3;    // 8 groups x 8 slices
  const int tid = threadIdx.x;
  const int w = tid >> 6, lane = tid & 63;
  const int bl = lane & 15, uq = lane >> 4;
  const int bglob = gid * 16 + bl;
  unsigned* line = bars + gid * 32;

  const int ti0 = sid * 16 + w * 2;           // tile indices ti0 (even), ti0+1
  const int ug0 = ((ti0 >> 3) << 5) + ((ti0 & 7) << 2) + uq;
  const int ti1 = ti0 + 1;
  const int ug1 = ((ti1 >> 3) << 5) + ((ti1 & 7) << 2) + uq;

  // A fragments for both tiles: register-resident for the whole launch
  bf16x8 afr0[16], afr1[16];
  {
    const ushort* b0 = WhhF + ((size_t)(ti0 * 16) * 64 + lane) * 8;
    const ushort* b1 = WhhF + ((size_t)(ti1 * 16) * 64 + lane) * 8;
#pragma unroll
    for (int kf = 0; kf < 16; ++kf) {
      afr0[kf] = *(const bf16x8*)(b0 + (size_t)kf * 512);
      afr1[kf] = *(const bf16x8*)(b1 + (size_t)kf * 512);
    }
  }

  float c0 = 0.f, c1 = 0.f;
  if (t0 > 0) {
    c0 = Cb[(size_t)bglob * RHc + ug0];
    c1 = Cb[(size_t)bglob * RHc + ug1];
  }
  ushort* hbg = hbuf + (size_t)gid * (2 * 16 * RHc);

  float4 gxa = *(const float4*)(GXc + ((size_t)0 * Bc + bglob) * G4c + ug0 * 4);
  float4 gxb = *(const float4*)(GXc + ((size_t)0 * Bc + bglob) * G4c + ug1 * 4);

  for (int s = 0; s < nsteps; ++s) {
    const int t = t0 + s;
    f32x4 acc0 = {0.f, 0.f, 0.f, 0.f};
    f32x4 acc1 = {0.f, 0.f, 0.f, 0.f};
    if (t > 0) {
      const ushort* hsrc = hbg + (size_t)((t & 1) ^ 1) * (16 * RHc) + (size_t)bl * RHc + uq * 8;
#pragma unroll
      for (int kf = 0; kf < 16; ++kf) {
        const bf16x8 bf = *(const bf16x8*)(hsrc + kf * 32);
        acc0 = __builtin_amdgcn_mfma_f32_16x16x32_bf16(afr0[kf], bf, acc0, 0, 0, 0);
        acc1 = __builtin_amdgcn_mfma_f32_16x16x32_bf16(afr1[kf], bf, acc1, 0, 0, 0);
      }
    }
    // epilogue tile 0
    {
      const float iv = sigmoidf_(gxa.x + acc0[0]);
      const float fv = sigmoidf_(gxa.y + acc0[1]);
      const float gv = tanhf_(gxa.z + acc0[2]);
      const float ov = sigmoidf_(gxa.w + acc0[3]);
      c0 = fmaf(fv, c0, iv * gv);
      const float hval = ov * tanhf_(c0);
      hbg[(size_t)(t & 1) * (16 * RHc) + (size_t)bl * RHc + ug0] = f2bf(hval);
      Hch[((size_t)s * Bc + bglob) * RHc + ug0] = hval;
    }
    // epilogue tile 1
    {
      const float iv = sigmoidf_(gxb.x + acc1[0]);
      const float fv = sigmoidf_(gxb.y + acc1[1]);
      const float gv = tanhf_(gxb.z + acc1[2]);
      const float ov = sigmoidf_(gxb.w + acc1[3]);
      c1 = fmaf(fv, c1, iv * gv);
      const float hval = ov * tanhf_(c1);
      hbg[(size_t)(t & 1) * (16 * RHc) + (size_t)bl * RHc + ug1] = f2bf(hval);
      Hch[((size_t)s * Bc + bglob) * RHc + ug1] = hval;
    }
    if (s != nsteps - 1) {
      // prefetch next step's GX (independent of h) before the barrier spin
      gxa = *(const float4*)(GXc + ((size_t)(s + 1) * Bc + bglob) * G4c + ug0 * 4);
      gxb = *(const float4*)(GXc + ((size_t)(s + 1) * Bc + bglob) * G4c + ug1 * 4);
      group_barrier(line);
    }
  }
  Cb[(size_t)bglob * RHc + ug0] = c0;
  Cb[(size_t)bglob * RHc + ug1] = c1;
}

// one wave per (tl,b): y = h @ W_tag^T + b_tag, LayerNorm over NT=10
__global__ __launch_bounds__(256) void tag_ln_k(
    const float* __restrict__ Hch, const float* __restrict__ Wtag,
    const float* __restrict__ btag, const float* __restrict__ lng,
    const float* __restrict__ lnb, float* __restrict__ out, int t0)
{
  const int wid = (blockIdx.x * blockDim.x + threadIdx.x) >> 6;
  const int lane = threadIdx.x & 63;
  const int tl = wid >> 7, b = wid & 127;
  const int t = t0 + tl;
  const float* hp = Hch + ((size_t)tl * Bc + b) * RHc;
  float y[NTc];
#pragma unroll
  for (int j = 0; j < NTc; ++j) y[j] = 0.f;
  for (int k = lane; k < RHc; k += 64) {
    const float hv = hp[k];
#pragma unroll
    for (int j = 0; j < NTc; ++j)
      y[j] = fmaf(hv, Wtag[(size_t)j * RHc + k], y[j]);
  }
#pragma unroll
  for (int off = 32; off > 0; off >>= 1)
#pragma unroll
    for (int j = 0; j < NTc; ++j)
      y[j] += __shfl_xor(y[j], off);
  float mu = 0.f;
#pragma unroll
  for (int j = 0; j < NTc; ++j) { y[j] += btag[j]; mu += y[j]; }
  mu *= (1.0f / NTc);
  float var = 0.f;
#pragma unroll
  for (int j = 0; j < NTc; ++j) { const float d = y[j] - mu; var = fmaf(d, d, var); }
  var *= (1.0f / NTc);
  const float inv = rsqrtf(var + LNEPS);
  if (lane < NTc) {
    out[(size_t)b * NTc * Tc + (size_t)lane * Tc + t] =
        (y[lane] - mu) * inv * lng[lane] + lnb[lane];
  }
}

extern "C" void kernel_launch(void* const* d_in, const int* in_sizes, int n_in,
                              void* d_out, int out_size, void* d_ws, size_t ws_size,
                              hipStream_t stream)
{
  const float* slot = (const float*)d_in[0];
  const float* utt  = (const float*)d_in[1];
  const float* Wq = (const float*)d_in[2];   const float* bq = (const float*)d_in[3];
  const float* Wk = (const float*)d_in[4];   const float* bk = (const float*)d_in[5];
  const float* Wv = (const float*)d_in[6];   const float* bv = (const float*)d_in[7];
  const float* Wo = (const float*)d_in[8];   const float* bo = (const float*)d_in[9];
  const float* W_in = (const float*)d_in[10]; const float* b_in = (const float*)d_in[11];
  const float* W_ih = (const float*)d_in[12]; const float* W_hh = (const float*)d_in[13];
  const float* b_ih = (const float*)d_in[14]; const float* b_hh = (const float*)d_in[15];
  const float* W_tag = (const float*)d_in[16]; const float* b_tag = (const float*)d_in[17];
  const float* ln_g = (const float*)d_in[18]; const float* ln_b = (const float*)d_in[19];
  float* out = (float*)d_out;
  float* ws = (float*)d_ws;

  // adaptive chunk (floats): fixed = 2,265,088; per-chunk = 360,448
  int CHT = 16;
  while (CHT > 2 && 4ull * (2265088ull + 360448ull * (unsigned)CHT) > ws_size)
    CHT >>= 1;
  const int NCH = Tc / CHT;

  float* Xc    = ws;                          // 98304
  float* Xo    = Xc + 98304;                  // 98304
  float* bsum  = Xo + 98304;                  // 2048
  float* Cb    = bsum + 2048;                 // 65536
  float* Att   = Cb + 65536;                  // 196608
  ushort* hbuf = (ushort*)(Att + 196608);     // 131072 us (65536 f)
  ushort* WinB = (ushort*)(ws + 526336);      // 786432 us (393216 f)
  ushort* WihB = (ushort*)(ws + 919552);      // 1048576 us (524288 f)
  ushort* WoB  = (ushort*)(ws + 1443840);     // 589824 us (294912 f)
  ushort* WhhF = (ushort*)(ws + 1738752);     // 1048576 us (524288 f)
  float* cqB   = ws + 2263040;                // 1536
  unsigned* bars = (unsigned*)(ws + 2264576); // 512 u32 (8 grp x 128B lines)
  // loop region: LINc bf16, GXc f32, Hch f32; Pb overlays it (pre-loop only)
  ushort* LINc = (ushort*)(ws + 2265088);                    // 65536*CHT us
  float* GXc   = ws + 2265088 + (size_t)32768 * CHT;         // 262144*CHT f
  float* Hch   = GXc + (size_t)262144 * CHT;                 // 65536*CHT f
  ushort* Pb   = (ushort*)(ws + 2265088);                    // overlay

  (void)hipMemsetAsync(bars, 0, 2048, stream);

  // weight conversions + bias sum (W_ih rows permuted to gate-interleaved)
  hipLaunchKernelGGL(cvt4_k, dim3(768), dim3(256), 0, stream, W_in, WinB, 196608);
  hipLaunchKernelGGL(cvt_wih_perm_k, dim3(2048), dim3(256), 0, stream, W_ih, WihB);
  hipLaunchKernelGGL(cvt4_k, dim3(576), dim3(256), 0, stream, Wo, WoB, 147456);
  hipLaunchKernelGGL(cvt_whh_frag_k, dim3(512), dim3(256), 0, stream, W_hh, WhhF);
  hipLaunchKernelGGL(bias_sum_perm_k, dim3(8), dim3(256), 0, stream, b_ih, b_hh, bsum);

  // attention
  hipLaunchKernelGGL(fold_qp_k, dim3(Bc * NHEAD), dim3(256), 0, stream,
                     slot, Wq, bq, Wk, bk, Pb, cqB);
  hipLaunchKernelGGL(attn_scores2_k, dim3(Bc), dim3(256), 0, stream, Pb, cqB, utt, Att);
  hipLaunchKernelGGL(attn_uxc_k, dim3(Bc), dim3(256), 0, stream, Att, utt, Wv, bv, Xc);
  hipLaunchKernelGGL(bgemm_bt, dim3(6, 1), dim3(256), 0, stream,
                     (const void*)Xc, WoB, bo, (void*)Xo, 128, 768, 768, 0, 0,
                     (const float*)nullptr, (const float*)nullptr, 0);

  // chunked precompute + MFMA LSTM + chunked tag/LN
  for (int tc = 0; tc < NCH; ++tc) {
    hipLaunchKernelGGL(bgemm_bt, dim3(4, CHT), dim3(256), 0, stream,
                       (const void*)nullptr, WinB, b_in, (void*)LINc,
                       CHT * Bc, 512, 1536, 1, 1, utt, Xo, tc * CHT);
    hipLaunchKernelGGL(bgemm_bt, dim3(16, CHT), dim3(256), 0, stream,
                       (const void*)LINc, WihB, bsum, (void*)GXc,
                       CHT * Bc, 2048, 512, 2, 0,
                       (const float*)nullptr, (const float*)nullptr, 0);
    hipLaunchKernelGGL(lstm_mfma_k, dim3(64), dim3(512), 0, stream,
                       WhhF, GXc, hbuf, Hch, Cb, tc * CHT, CHT, bars);
    hipLaunchKernelGGL(tag_ln_k, dim3(CHT * 32), dim3(256), 0, stream,
                       Hch, W_tag, b_tag, ln_g, ln_b, out, tc * CHT);
  }
}